// Round 5
// baseline (76.740 us; speedup 1.0000x reference)
//
#include <hip/hip_runtime.h>

#define NB 256
#define NS 2048
#define NP 64
#define ND 80
#define STILE 64
#define NTILE 32            // NS/STILE
#define NTHREADS 512

typedef __attribute__((ext_vector_type(4))) float f32x4;
typedef __attribute__((ext_vector_type(8))) short bf16x8;
typedef __attribute__((ext_vector_type(4))) unsigned short u16x4;
typedef unsigned short u16;

// ---------------- LDS layout (bytes) ----------------
// eh   u16[2][64][104] @ 0      (26624)  bf16-RNE of enc [s][d], K-pad 80..95 zeroed once
// el   u16[2][64][104] @ 26624  (26624)  bf16 residual
// ehP  u16[2][5120]    @ 53248  (20480)  tr_b16 subtiles: region(q,n)=(q*5+n)*256 u16,
//                                         pos = 64*((s&15)>>2) + 16*(s&3) + d_local
// mfull int[2048]      @ 73728  (8192)   whole mask row, loaded once
// mst  f32[4][64]      @ 81920  (1024);  lst @ 82944 (1024);  modep @ 83968
// prologue overlay: W f32[80][84]@0 ; dec f32[64][84]@26880 ; qtmp f32[64][100]@0
// epilogue overlay: cacc f32[64][84]@0
#define SMEM_BYTES 84032

__device__ __forceinline__ float bft(float f) {
  return __uint_as_float(__float_as_uint(f) & 0xFFFF0000u);
}
__device__ __forceinline__ u16 h16(float f) { return (u16)(__float_as_uint(f) >> 16); }
__device__ __forceinline__ u16 h16r(float f) {  // round-to-nearest-even bf16
  unsigned u = __float_as_uint(f);
  u += 0x7FFFu + ((u >> 16) & 1u);
  return (u16)(u >> 16);
}
__device__ __forceinline__ unsigned pack2r(float lo, float hi) {
  return (unsigned)h16r(lo) | ((unsigned)h16r(hi) << 16);
}

// 16x16 K=32 bf16 MFMA. C/D: col=lane&15, row=4*(lane>>4)+r [guide m89/m91].
// A and B share the (lane-group, reg-slot)->k map; identical slot placement on
// both sides contracts correctly regardless of internal k permutation.
__device__ __forceinline__ f32x4 mfma32(bf16x8 a, bf16x8 b, f32x4 c) {
  return __builtin_amdgcn_mfma_f32_16x16x32_bf16(a, b, c, 0, 0, 0);
}

__global__ __launch_bounds__(NTHREADS, 2)
void DecoderAttention_62989990363717_kernel(const float* __restrict__ enc,
                                            const float* __restrict__ dec,
                                            const int* __restrict__ maskp,
                                            const float* __restrict__ W,
                                            float* __restrict__ out)
{
  __shared__ __align__(16) char smem[SMEM_BYTES];

  u16* eh    = (u16*)smem;                // [2][64][104]
  u16* el    = (u16*)(smem + 26624);
  u16* ehP   = (u16*)(smem + 53248);      // [2][5120]
  int* mfull = (int*)(smem + 73728);      // [2048]
  float* mst = (float*)(smem + 81920);    // [4][64]
  float* lst = (float*)(smem + 82944);    // [4][64]
  int* modep = (int*)(smem + 83968);

  const int tid  = (int)threadIdx.x;
  const int lane = tid & 63;
  const int wv   = tid >> 6;    // 0..7
  const int hq   = wv >> 1;     // s-quarter: [16*hq, 16*hq+16)
  const int ph   = wv & 1;      // p-half: p-blocks 2ph, 2ph+1
  const int l15  = lane & 15;
  const int g    = lane >> 4;
  const int b    = (int)blockIdx.x;

  const float* encB = enc + (size_t)b * NS * ND;
  const float* decB = dec + (size_t)b * NP * ND;

  // ---------- prologue: W, dec -> LDS; mask-mode; full mask preload; Q ----------
  {
    float* Wl = (float*)smem;            // [80][84]
    float* dl = (float*)(smem + 26880);  // [64][84]
    for (int i = tid; i < 80 * 80; i += NTHREADS) Wl[(i / 80) * 84 + (i % 80)] = W[i];
    for (int i = tid; i < 64 * 80; i += NTHREADS) dl[(i / 80) * 84 + (i % 80)] = decB[i];
    if (tid == 0) {
      const unsigned* mw = (const unsigned*)maskp;
      int ok = 1;
      for (int i = 0; i < 16; ++i) ok &= (mw[i] <= 1u);
      *modep = ok;   // 1 => int32 mask, 0 => int8 mask
    }
    __syncthreads();
    const int m32 = *modep;
    if (m32) {
#pragma unroll
      for (int k = 0; k < 4; ++k) mfull[tid + 512 * k] = maskp[(size_t)b * NS + tid + 512 * k];
    } else {
      unsigned w = ((const unsigned*)maskp)[(size_t)b * (NS / 4) + tid];
      int4 mm = make_int4((int)(w & 255u), (int)((w >> 8) & 255u),
                          (int)((w >> 16) & 255u), (int)(w >> 24));
      *(int4*)&mfull[4 * tid] = mm;
    }
    // Q = dec @ W^T in fp32 (p = tid&63, e-range = 10*qw)
    float qa[10];
    const int qp = tid & 63, qw = tid >> 6;
#pragma unroll
    for (int j = 0; j < 10; ++j) qa[j] = 0.f;
    for (int kg = 0; kg < 20; ++kg) {
      f32x4 dv = *(const f32x4*)&dl[qp * 84 + kg * 4];
#pragma unroll
      for (int j = 0; j < 10; ++j) {
        f32x4 wv4 = *(const f32x4*)&Wl[(qw * 10 + j) * 84 + kg * 4];
        qa[j] = fmaf(dv.x, wv4.x, qa[j]);
        qa[j] = fmaf(dv.y, wv4.y, qa[j]);
        qa[j] = fmaf(dv.z, wv4.z, qa[j]);
        qa[j] = fmaf(dv.w, wv4.w, qa[j]);
      }
    }
    __syncthreads();            // Wl/dl reads done
    float* qtmp = (float*)smem; // [64][100], zeros at d=80..95
#pragma unroll
    for (int j = 0; j < 10; ++j) qtmp[qp * 100 + qw * 10 + j] = qa[j];
    if (qw == 7) {
#pragma unroll
      for (int z = 0; z < 16; ++z) qtmp[qp * 100 + 80 + z] = 0.f;
    }
    __syncthreads();
  }

  // ---------- Q fragments (persistent, bf16 hi/lo split, 2 p-blocks) ----------
  bf16x8 qb[2][3], qlb[2][3];
  {
    const float* qtmp = (const float*)smem;
#pragma unroll
    for (int nt = 0; nt < 2; ++nt) {
      const int prow = 32 * ph + 16 * nt + l15;
#pragma unroll
      for (int kk = 0; kk < 3; ++kk) {
        const int d0 = kk * 32 + g * 8;
        f32x4 f0 = *(const f32x4*)&qtmp[prow * 100 + d0];
        f32x4 f1 = *(const f32x4*)&qtmp[prow * 100 + d0 + 4];
        float fq[8] = {f0.x, f0.y, f0.z, f0.w, f1.x, f1.y, f1.z, f1.w};
        union { u16 u[8]; bf16x8 v; } H, L;
#pragma unroll
        for (int j = 0; j < 8; ++j) {
          H.u[j] = h16(fq[j]);
          L.u[j] = h16(fq[j] - bft(fq[j]));
        }
        qb[nt][kk] = H.v; qlb[nt][kk] = L.v;
      }
    }
  }
  __syncthreads();   // qtmp dead; staging may overwrite

  // ---------- zero K-pad (d=80..95) once, both buffers ----------
  if (tid < 256) {
    const int arr = tid >> 7, buf = (tid >> 6) & 1, s = tid & 63;
    u16* p = (arr ? el : eh) + buf * 6656 + s * 104 + 80;
    *(uint4*)p = make_uint4(0u, 0u, 0u, 0u);
    *(uint4*)(p + 8) = make_uint4(0u, 0u, 0u, 0u);
  }

  // loader roles: tid<320 stage enc (5 threads/row, 16 f32 each, all-b128 writes)
  const bool ldr = (tid < 320);
  const int srow = tid / 5;                 // 0..63
  const int c    = tid - srow * 5;          // 0..4 (d-block)
  u16* ehW = eh + srow * 104 + 16 * c;
  u16* elW = el + srow * 104 + 16 * c;
  u16* ePW = ehP + ((srow >> 4) * 5 + c) * 256 + ((srow & 15) >> 2) * 64 + (srow & 3) * 16;
  const float* gsrc = encB + srow * ND + 16 * c;

#define STAGE_WRITE(bi)                                                          \
  do {                                                                           \
    if (ldr) {                                                                   \
      float fv[16] = {r0.x, r0.y, r0.z, r0.w, r1.x, r1.y, r1.z, r1.w,            \
                      r2.x, r2.y, r2.z, r2.w, r3.x, r3.y, r3.z, r3.w};           \
      unsigned hh[8], ll[8];                                                     \
      _Pragma("unroll")                                                          \
      for (int q = 0; q < 8; ++q) {                                              \
        float flo = fv[2*q], fhi = fv[2*q+1];                                    \
        unsigned h = pack2r(flo, fhi);                                           \
        hh[q] = h;                                                               \
        float rlo = flo - __uint_as_float(h << 16);                              \
        float rhi = fhi - __uint_as_float(h & 0xFFFF0000u);                      \
        ll[q] = pack2r(rlo, rhi);                                                \
      }                                                                          \
      u16* eh_ = ehW + (bi) * 6656;                                              \
      u16* el_ = elW + (bi) * 6656;                                              \
      u16* eP_ = ePW + (bi) * 5120;                                              \
      *(uint4*)eh_       = make_uint4(hh[0], hh[1], hh[2], hh[3]);               \
      *(uint4*)(eh_ + 8) = make_uint4(hh[4], hh[5], hh[6], hh[7]);               \
      *(uint4*)el_       = make_uint4(ll[0], ll[1], ll[2], ll[3]);               \
      *(uint4*)(el_ + 8) = make_uint4(ll[4], ll[5], ll[6], ll[7]);               \
      *(uint4*)eP_       = make_uint4(hh[0], hh[1], hh[2], hh[3]);               \
      *(uint4*)(eP_ + 8) = make_uint4(hh[4], hh[5], hh[6], hh[7]);               \
    }                                                                            \
  } while (0)

  // ---------- stage tile 0 ----------
  {
    f32x4 r0, r1, r2, r3;
    if (ldr) {
      r0 = *(const f32x4*)gsrc;       r1 = *(const f32x4*)(gsrc + 4);
      r2 = *(const f32x4*)(gsrc + 8); r3 = *(const f32x4*)(gsrc + 12);
    }
    STAGE_WRITE(0);
    __syncthreads();
  }

  // ---------- main loop ----------
  f32x4 ctx0[5], ctx1[5];
#pragma unroll
  for (int n = 0; n < 5; ++n) { ctx0[n] = (f32x4){0.f,0.f,0.f,0.f}; ctx1[n] = (f32x4){0.f,0.f,0.f,0.f}; }
  float mr0 = -3.0e38f, mr1 = -3.0e38f, lr0 = 0.f, lr1 = 0.f;

  // tr-read base: region(hq, 0), per-lane natural addressing (+8*lane bytes)
  const unsigned trBase = (unsigned)(uintptr_t)ehP + (unsigned)(hq * 5 * 512 + 8 * lane);

  for (int tt = 0; tt < NTILE; ++tt) {
    const int cur = tt & 1, nxt = cur ^ 1;
    const bool hn = (tt + 1 < NTILE);
    f32x4 r0, r1, r2, r3;
    if (hn && ldr) {   // issue next-tile loads early (consumed at STAGE_WRITE)
      const float* src = gsrc + (size_t)(tt + 1) * STILE * ND;
      r0 = *(const f32x4*)src;       r1 = *(const f32x4*)(src + 4);
      r2 = *(const f32x4*)(src + 8); r3 = *(const f32x4*)(src + 12);
    }

    // ---- QK^T (swapped): D'[s][p] = E * Q^T, K=96, 3-term bf16 split ----
    const u16* ehR = eh + cur * 6656 + (16 * hq + l15) * 104;
    const u16* elR = el + cur * 6656 + (16 * hq + l15) * 104;
    bf16x8 ea[3], ec[3];
#pragma unroll
    for (int kk = 0; kk < 3; ++kk) {
      ea[kk] = *(const bf16x8*)&ehR[kk * 32 + g * 8];
      ec[kk] = *(const bf16x8*)&elR[kk * 32 + g * 8];
    }
    f32x4 a0 = (f32x4){0.f,0.f,0.f,0.f}, a1 = (f32x4){0.f,0.f,0.f,0.f};
#pragma unroll
    for (int kk = 0; kk < 3; ++kk) {   // two independent chains interleaved
      a0 = mfma32(ea[kk], qb[0][kk], a0);
      a1 = mfma32(ea[kk], qb[1][kk], a1);
      a0 = mfma32(ec[kk], qb[0][kk], a0);
      a1 = mfma32(ec[kk], qb[1][kk], a1);
      a0 = mfma32(ea[kk], qlb[0][kk], a0);
      a1 = mfma32(ea[kk], qlb[1][kk], a1);
    }

    // ---- masked online softmax (rows = s, per-lane col = p), defer-max ----
    int4 mki = *(const int4*)&mfull[tt * 64 + 16 * hq + 4 * g];
    float sv0[4], sv1[4];
    sv0[0] = mki.x ? -3.0e38f : a0[0]; sv1[0] = mki.x ? -3.0e38f : a1[0];
    sv0[1] = mki.y ? -3.0e38f : a0[1]; sv1[1] = mki.y ? -3.0e38f : a1[1];
    sv0[2] = mki.z ? -3.0e38f : a0[2]; sv1[2] = mki.z ? -3.0e38f : a1[2];
    sv0[3] = mki.w ? -3.0e38f : a0[3]; sv1[3] = mki.w ? -3.0e38f : a1[3];
    float tm0 = fmaxf(fmaxf(sv0[0], sv0[1]), fmaxf(sv0[2], sv0[3]));
    tm0 = fmaxf(tm0, __shfl_xor(tm0, 16)); tm0 = fmaxf(tm0, __shfl_xor(tm0, 32));
    float tm1 = fmaxf(fmaxf(sv1[0], sv1[1]), fmaxf(sv1[2], sv1[3]));
    tm1 = fmaxf(tm1, __shfl_xor(tm1, 16)); tm1 = fmaxf(tm1, __shfl_xor(tm1, 32));
    const bool need = !__all((tm0 <= mr0 + 8.0f) && (tm1 <= mr1 + 8.0f));
    if (need) {
      float mn0 = fmaxf(mr0, tm0), mn1 = fmaxf(mr1, tm1);
      float esc0 = __expf(mr0 - mn0), esc1 = __expf(mr1 - mn1);
      lr0 *= esc0; lr1 *= esc1;
      mr0 = mn0; mr1 = mn1;
      float fr0[4], fr1[4];
#pragma unroll
      for (int rr = 0; rr < 4; ++rr) {
        fr0[rr] = __shfl(esc0, 4 * g + rr);
        fr1[rr] = __shfl(esc1, 4 * g + rr);
      }
#pragma unroll
      for (int n = 0; n < 5; ++n) {
#pragma unroll
        for (int rr = 0; rr < 4; ++rr) { ctx0[n][rr] *= fr0[rr]; ctx1[n][rr] *= fr1[rr]; }
      }
    }
    float p0[4], p1[4];
#pragma unroll
    for (int rr = 0; rr < 4; ++rr) { p0[rr] = __expf(sv0[rr] - mr0); p1[rr] = __expf(sv1[rr] - mr1); }
    float u0 = p0[0] + p0[1] + p0[2] + p0[3];
    u0 += __shfl_xor(u0, 16); u0 += __shfl_xor(u0, 32);
    float u1 = p1[0] + p1[1] + p1[2] + p1[3];
    u1 += __shfl_xor(u1, 16); u1 += __shfl_xor(u1, 32);
    lr0 += u0; lr1 += u1;

    // ---- PV: ctx[p][d] += P[p][s16] * E[s16][d]; B via ds_read_b64_tr_b16 ----
    // delivered[j] = E[s=16hq+4g+j][d=16n+l15]  (slots 0..3, matching PA slots)
    union { unsigned uu[4]; bf16x8 v; } PA0, PA1;
    PA0.uu[0] = pack2r(p0[0], p0[1]); PA0.uu[1] = pack2r(p0[2], p0[3]);
    PA0.uu[2] = 0u; PA0.uu[3] = 0u;
    PA1.uu[0] = pack2r(p1[0], p1[1]); PA1.uu[1] = pack2r(p1[2], p1[3]);
    PA1.uu[2] = 0u; PA1.uu[3] = 0u;
    const unsigned tra = trBase + (unsigned)(cur * 10240);
    u16x4 tv0, tv1, tv2, tv3, tv4;
    asm volatile("ds_read_b64_tr_b16 %0, %1"             : "=v"(tv0) : "v"(tra));
    asm volatile("ds_read_b64_tr_b16 %0, %1 offset:512"  : "=v"(tv1) : "v"(tra));
    asm volatile("ds_read_b64_tr_b16 %0, %1 offset:1024" : "=v"(tv2) : "v"(tra));
    asm volatile("ds_read_b64_tr_b16 %0, %1 offset:1536" : "=v"(tv3) : "v"(tra));
    asm volatile("ds_read_b64_tr_b16 %0, %1 offset:2048" : "=v"(tv4) : "v"(tra));
    asm volatile("s_waitcnt lgkmcnt(0)" ::: "memory");
    __builtin_amdgcn_sched_barrier(0);
#define PVN(n, tvn)                                                              \
    {                                                                            \
      bf16x8 bb = { (short)(tvn)[0], (short)(tvn)[1], (short)(tvn)[2],           \
                    (short)(tvn)[3], 0, 0, 0, 0 };                               \
      ctx0[n] = mfma32(PA0.v, bb, ctx0[n]);                                      \
      ctx1[n] = mfma32(PA1.v, bb, ctx1[n]);                                      \
    }
    PVN(0, tv0) PVN(1, tv1) PVN(2, tv2) PVN(3, tv3) PVN(4, tv4)
#undef PVN

    if (hn) { STAGE_WRITE(nxt); }
    __syncthreads();
  }

  // ---------- epilogue: merge 4 s-quarters, normalize, write ----------
  if (g == 0) {
    const int pb = 32 * ph + l15;
    mst[hq * 64 + pb] = mr0;      lst[hq * 64 + pb] = lr0;
    mst[hq * 64 + pb + 16] = mr1; lst[hq * 64 + pb + 16] = lr1;
  }
  __syncthreads();
  float F0, F1;
  {
    const int p0i = 32 * ph + l15, p1i = p0i + 16;
    float M0 = fmaxf(fmaxf(mst[p0i], mst[64 + p0i]), fmaxf(mst[128 + p0i], mst[192 + p0i]));
    float M1 = fmaxf(fmaxf(mst[p1i], mst[64 + p1i]), fmaxf(mst[128 + p1i], mst[192 + p1i]));
    F0 = __expf(mr0 - M0); F1 = __expf(mr1 - M1);
  }
  float g0[4], g1[4];
#pragma unroll
  for (int rr = 0; rr < 4; ++rr) { g0[rr] = __shfl(F0, 4 * g + rr); g1[rr] = __shfl(F1, 4 * g + rr); }
  float* cacc = (float*)smem;  // [64][84]
  for (int qq = 0; qq < 4; ++qq) {
    if (hq == qq) {
#pragma unroll
      for (int n = 0; n < 5; ++n) {
#pragma unroll
        for (int rr = 0; rr < 4; ++rr) {
          const int row0 = 32 * ph + 4 * g + rr;
          const int col = 16 * n + l15;
          float v0 = ctx0[n][rr] * g0[rr];
          float v1 = ctx1[n][rr] * g1[rr];
          if (qq == 0) { cacc[row0 * 84 + col] = v0; cacc[(row0 + 16) * 84 + col] = v1; }
          else         { cacc[row0 * 84 + col] += v0; cacc[(row0 + 16) * 84 + col] += v1; }
        }
      }
    }
    __syncthreads();
  }
  {
    const int op = tid >> 3, oc = tid & 7, od0 = oc * 10;
    float Mv = fmaxf(fmaxf(mst[op], mst[64 + op]), fmaxf(mst[128 + op], mst[192 + op]));
    float Lv = lst[op] * __expf(mst[op] - Mv) + lst[64 + op] * __expf(mst[64 + op] - Mv)
             + lst[128 + op] * __expf(mst[128 + op] - Mv) + lst[192 + op] * __expf(mst[192 + op] - Mv);
    float inv = 1.0f / Lv;
    float* orow = out + ((size_t)b * NP + op) * ND;
#pragma unroll
    for (int i = 0; i < 10; i += 2) {
      float2 v;
      v.x = cacc[op * 84 + od0 + i] * inv;
      v.y = cacc[op * 84 + od0 + i + 1] * inv;
      *(float2*)&orow[od0 + i] = v;
    }
  }
}

extern "C" void kernel_launch(void* const* d_in, const int* in_sizes, int n_in,
                              void* d_out, int out_size, void* d_ws, size_t ws_size,
                              hipStream_t stream) {
  (void)in_sizes; (void)n_in; (void)out_size; (void)d_ws; (void)ws_size;
  const float* enc  = (const float*)d_in[0];
  const float* dec  = (const float*)d_in[1];
  const int*   mask = (const int*)d_in[2];
  const float* W    = (const float*)d_in[3];
  float* out = (float*)d_out;
  DecoderAttention_62989990363717_kernel<<<dim3(NB), dim3(NTHREADS), 0, stream>>>(
      enc, dec, mask, W, out);
}

// Round 6
// 64.881 us; speedup vs baseline: 1.1828x; 1.1828x over previous
//
#include <hip/hip_runtime.h>

#define NB 256
#define NS 2048
#define NP 64
#define ND 80
#define STILE 64
#define NTILE 32            // NS/STILE
#define NTHREADS 1024

typedef __attribute__((ext_vector_type(4))) float f32x4;
typedef __attribute__((ext_vector_type(8))) short bf16x8;
typedef __attribute__((ext_vector_type(4))) unsigned short u16x4;
typedef unsigned short u16;

// ---------------- LDS layout (bytes) ----------------
// eh   u16[2][64][104] @ 0      (26624)  bf16-RNE of enc [s][d], K-pad 80..95 zeroed once
// el   u16[2][64][104] @ 26624  (26624)  bf16 residual
// ehP  u16[2][5440]    @ 53248  (21760)  tr_b16 subtiles: region(q,n) = (q*5+n)*272 u16
//                                         (272 = 256 + 16 pad: de-conflicts staging writes),
//                                         pos-in-region = 64*((s&15)>>2) + 16*(s&3) + (d&15)
// mfull int[2048]      @ 75008  (8192)   whole mask row, loaded once in prologue
// mst  f32[4][64]      @ 83200 (1024);  lst @ 84224 (1024);  modep @ 85248
// prologue overlay: W f32[80][84]@0 ; dec f32[64][84]@26880 ; qtmp f32[64][100]@0
// epilogue overlay: cacc f32[64][84]@0
#define SMEM_BYTES 85312

__device__ __forceinline__ float bft(float f) {
  return __uint_as_float(__float_as_uint(f) & 0xFFFF0000u);
}
__device__ __forceinline__ u16 h16(float f) { return (u16)(__float_as_uint(f) >> 16); }
__device__ __forceinline__ u16 h16r(float f) {  // round-to-nearest-even bf16
  unsigned u = __float_as_uint(f);
  u += 0x7FFFu + ((u >> 16) & 1u);
  return (u16)(u >> 16);
}
__device__ __forceinline__ unsigned pack2r(float lo, float hi) {
  return (unsigned)h16r(lo) | ((unsigned)h16r(hi) << 16);
}

// 16x16 K=32 bf16 MFMA. C/D: col=lane&15, row=4*(lane>>4)+r [guide m89/m91].
__device__ __forceinline__ f32x4 mfma32(bf16x8 a, bf16x8 b, f32x4 c) {
  return __builtin_amdgcn_mfma_f32_16x16x32_bf16(a, b, c, 0, 0, 0);
}

__global__ __launch_bounds__(NTHREADS, 4)
void DecoderAttention_62989990363717_kernel(const float* __restrict__ enc,
                                            const float* __restrict__ dec,
                                            const int* __restrict__ maskp,
                                            const float* __restrict__ W,
                                            float* __restrict__ out)
{
  __shared__ __align__(16) char smem[SMEM_BYTES];

  u16* eh    = (u16*)smem;                // [2][64][104]
  u16* el    = (u16*)(smem + 26624);
  u16* ehP   = (u16*)(smem + 53248);      // [2][5440]
  int* mfull = (int*)(smem + 75008);      // [2048]
  float* mst = (float*)(smem + 83200);    // [4][64]
  float* lst = (float*)(smem + 84224);    // [4][64]
  int* modep = (int*)(smem + 85248);

  const int tid  = (int)threadIdx.x;
  const int lane = tid & 63;
  const int wv   = tid >> 6;    // 0..15
  const int pp   = wv & 3;      // p-block: rows [16*pp, 16*pp+16)
  const int hq   = wv >> 2;     // s-quarter within tile: [16*hq, 16*hq+16)
  const int l15  = lane & 15;
  const int g    = lane >> 4;
  const int b    = (int)blockIdx.x;

  const float* encB = enc + (size_t)b * NS * ND;
  const float* decB = dec + (size_t)b * NP * ND;

  // ---------- prologue: W, dec -> LDS; mask-mode; full mask preload; Q ----------
  {
    float* Wl = (float*)smem;            // [80][84]
    float* dl = (float*)(smem + 26880);  // [64][84]
    for (int i = tid; i < 80 * 80; i += NTHREADS) Wl[(i / 80) * 84 + (i % 80)] = W[i];
    for (int i = tid; i < 64 * 80; i += NTHREADS) dl[(i / 80) * 84 + (i % 80)] = decB[i];
    if (tid == 0) {
      const unsigned* mw = (const unsigned*)maskp;
      int ok = 1;
      for (int i = 0; i < 16; ++i) ok &= (mw[i] <= 1u);
      *modep = ok;   // 1 => int32 mask, 0 => int8 mask
    }
    __syncthreads();
    const int m32 = *modep;
    if (m32) {
      mfull[tid]        = maskp[(size_t)b * NS + tid];
      mfull[tid + 1024] = maskp[(size_t)b * NS + tid + 1024];
    } else if (tid < 512) {
      unsigned w = ((const unsigned*)maskp)[(size_t)b * (NS / 4) + tid];
      int4 mm = make_int4((int)(w & 255u), (int)((w >> 8) & 255u),
                          (int)((w >> 16) & 255u), (int)(w >> 24));
      *(int4*)&mfull[4 * tid] = mm;
    }
    // Q = dec @ W^T in fp32 (512 threads: p = tid&63, e-range = 10*qw)
    float qa[10];
    const int qp = tid & 63, qw = (tid >> 6) & 7;
    if (tid < 512) {
#pragma unroll
      for (int j = 0; j < 10; ++j) qa[j] = 0.f;
      for (int kg = 0; kg < 20; ++kg) {
        f32x4 dv = *(const f32x4*)&dl[qp * 84 + kg * 4];
#pragma unroll
        for (int j = 0; j < 10; ++j) {
          f32x4 wv4 = *(const f32x4*)&Wl[(qw * 10 + j) * 84 + kg * 4];
          qa[j] = fmaf(dv.x, wv4.x, qa[j]);
          qa[j] = fmaf(dv.y, wv4.y, qa[j]);
          qa[j] = fmaf(dv.z, wv4.z, qa[j]);
          qa[j] = fmaf(dv.w, wv4.w, qa[j]);
        }
      }
    }
    __syncthreads();            // Wl/dl reads done
    float* qtmp = (float*)smem; // [64][100], zeros at d=80..95
    if (tid < 512) {
#pragma unroll
      for (int j = 0; j < 10; ++j) qtmp[qp * 100 + qw * 10 + j] = qa[j];
      if (qw == 7) {
#pragma unroll
        for (int z = 0; z < 16; ++z) qtmp[qp * 100 + 80 + z] = 0.f;
      }
    }
    __syncthreads();
  }

  // ---------- Q fragments (persistent, bf16 hi/lo split) ----------
  bf16x8 qb[3], qlb[3];
  {
    const float* qtmp = (const float*)smem;
    const int prow = 16 * pp + l15;
#pragma unroll
    for (int kk = 0; kk < 3; ++kk) {
      const int d0 = kk * 32 + g * 8;
      f32x4 f0 = *(const f32x4*)&qtmp[prow * 100 + d0];
      f32x4 f1 = *(const f32x4*)&qtmp[prow * 100 + d0 + 4];
      float fq[8] = {f0.x, f0.y, f0.z, f0.w, f1.x, f1.y, f1.z, f1.w};
      union { u16 u[8]; bf16x8 v; } H, L;
#pragma unroll
      for (int j = 0; j < 8; ++j) {
        H.u[j] = h16(fq[j]);
        L.u[j] = h16(fq[j] - bft(fq[j]));
      }
      qb[kk] = H.v; qlb[kk] = L.v;
    }
  }
  __syncthreads();   // qtmp dead; staging may overwrite

  // ---------- zero K-pad (d=80..95) once, both buffers ----------
  if (tid < 256) {
    const int arr = tid >> 7, buf = (tid >> 6) & 1, s = tid & 63;
    u16* p = (arr ? el : eh) + buf * 6656 + s * 104 + 80;
    *(uint4*)p = make_uint4(0u, 0u, 0u, 0u);
    *(uint4*)(p + 8) = make_uint4(0u, 0u, 0u, 0u);
  }

  // loader roles: tid<320 stage enc (5 threads/row, 16 f32 each, all-b128 writes)
  const bool ldr = (tid < 320);
  const int srow = tid / 5;                 // 0..63
  const int c    = tid - srow * 5;          // 0..4 (d-block of 16)
  u16* ehW = eh + srow * 104 + 16 * c;
  u16* elW = el + srow * 104 + 16 * c;
  u16* ePW = ehP + ((srow >> 4) * 5 + c) * 272 + ((srow & 15) >> 2) * 64 + (srow & 3) * 16;
  const float* gsrc = encB + srow * ND + 16 * c;

#define STAGE_WRITE(bi)                                                          \
  do {                                                                           \
    if (ldr) {                                                                   \
      float fv[16] = {r0.x, r0.y, r0.z, r0.w, r1.x, r1.y, r1.z, r1.w,            \
                      r2.x, r2.y, r2.z, r2.w, r3.x, r3.y, r3.z, r3.w};           \
      unsigned hh[8], ll[8];                                                     \
      _Pragma("unroll")                                                          \
      for (int q = 0; q < 8; ++q) {                                              \
        float flo = fv[2*q], fhi = fv[2*q+1];                                    \
        unsigned h = pack2r(flo, fhi);                                           \
        hh[q] = h;                                                               \
        float rlo = flo - __uint_as_float(h << 16);                              \
        float rhi = fhi - __uint_as_float(h & 0xFFFF0000u);                      \
        ll[q] = pack2r(rlo, rhi);                                                \
      }                                                                          \
      u16* eh_ = ehW + (bi) * 6656;                                              \
      u16* el_ = elW + (bi) * 6656;                                              \
      u16* eP_ = ePW + (bi) * 5440;                                              \
      *(uint4*)eh_       = make_uint4(hh[0], hh[1], hh[2], hh[3]);               \
      *(uint4*)(eh_ + 8) = make_uint4(hh[4], hh[5], hh[6], hh[7]);               \
      *(uint4*)el_       = make_uint4(ll[0], ll[1], ll[2], ll[3]);               \
      *(uint4*)(el_ + 8) = make_uint4(ll[4], ll[5], ll[6], ll[7]);               \
      *(uint4*)eP_       = make_uint4(hh[0], hh[1], hh[2], hh[3]);               \
      *(uint4*)(eP_ + 8) = make_uint4(hh[4], hh[5], hh[6], hh[7]);               \
    }                                                                            \
  } while (0)

  // ---------- stage tile 0 ----------
  {
    f32x4 r0, r1, r2, r3;
    if (ldr) {
      r0 = *(const f32x4*)gsrc;       r1 = *(const f32x4*)(gsrc + 4);
      r2 = *(const f32x4*)(gsrc + 8); r3 = *(const f32x4*)(gsrc + 12);
    }
    STAGE_WRITE(0);
    __syncthreads();
  }

  // ---------- main loop ----------
  f32x4 ctx[5];
#pragma unroll
  for (int n = 0; n < 5; ++n) ctx[n] = (f32x4){0.f, 0.f, 0.f, 0.f};
  float mr = -3.0e38f, lr = 0.f;

  // tr-read base: region(hq, 0), per-lane natural addressing (+8*lane bytes)
  const unsigned trBase = (unsigned)(uintptr_t)ehP + (unsigned)(hq * 5 * 544 + 8 * lane);

  for (int tt = 0; tt < NTILE; ++tt) {
    const int cur = tt & 1, nxt = cur ^ 1;
    const bool hn = (tt + 1 < NTILE);
    f32x4 r0, r1, r2, r3;
    if (hn && ldr) {   // issue next-tile loads early (consumed at STAGE_WRITE)
      const float* src = gsrc + (size_t)(tt + 1) * STILE * ND;
      r0 = *(const f32x4*)src;       r1 = *(const f32x4*)(src + 4);
      r2 = *(const f32x4*)(src + 8); r3 = *(const f32x4*)(src + 12);
    }

    // ---- QK^T (swapped): D'[s][p] = E * Q^T, K=96, 3-term bf16 split ----
    const u16* ehR = eh + cur * 6656 + (16 * hq + l15) * 104;
    const u16* elR = el + cur * 6656 + (16 * hq + l15) * 104;
    bf16x8 ea[3], ec[3];
#pragma unroll
    for (int kk = 0; kk < 3; ++kk) {
      ea[kk] = *(const bf16x8*)&ehR[kk * 32 + g * 8];
      ec[kk] = *(const bf16x8*)&elR[kk * 32 + g * 8];
    }
    f32x4 a = (f32x4){0.f, 0.f, 0.f, 0.f};
#pragma unroll
    for (int kk = 0; kk < 3; ++kk) {
      a = mfma32(ea[kk], qb[kk], a);
      a = mfma32(ec[kk], qb[kk], a);
      a = mfma32(ea[kk], qlb[kk], a);
    }

    // ---- masked online softmax (rows = s, per-lane col = p), defer-max ----
    int4 mki = *(const int4*)&mfull[tt * 64 + 16 * hq + 4 * g];
    float sv[4];
    sv[0] = mki.x ? -3.0e38f : a[0];
    sv[1] = mki.y ? -3.0e38f : a[1];
    sv[2] = mki.z ? -3.0e38f : a[2];
    sv[3] = mki.w ? -3.0e38f : a[3];
    float tm = fmaxf(fmaxf(sv[0], sv[1]), fmaxf(sv[2], sv[3]));
    tm = fmaxf(tm, __shfl_xor(tm, 16));
    tm = fmaxf(tm, __shfl_xor(tm, 32));
    const bool need = !__all(tm <= mr + 8.0f);
    if (need) {
      float mn = fmaxf(mr, tm);
      float esc = __expf(mr - mn);
      lr *= esc; mr = mn;
      float fr[4];
#pragma unroll
      for (int rr = 0; rr < 4; ++rr) fr[rr] = __shfl(esc, 4 * g + rr);
#pragma unroll
      for (int n = 0; n < 5; ++n) {
#pragma unroll
        for (int rr = 0; rr < 4; ++rr) ctx[n][rr] *= fr[rr];
      }
    }
    float p[4];
#pragma unroll
    for (int rr = 0; rr < 4; ++rr) p[rr] = __expf(sv[rr] - mr);
    float u = p[0] + p[1] + p[2] + p[3];
    u += __shfl_xor(u, 16); u += __shfl_xor(u, 32);
    lr += u;

    // ---- PV: ctx[p][d] += P[p][s16] * E[s16][d]; B via ds_read_b64_tr_b16 ----
    // delivered[j] = E[s=16hq+4g+j][d=16n+l15]  (slots 0..3, matching PA slots)
    union { unsigned uu[4]; bf16x8 v; } PA;
    PA.uu[0] = pack2r(p[0], p[1]); PA.uu[1] = pack2r(p[2], p[3]);
    PA.uu[2] = 0u; PA.uu[3] = 0u;
    const unsigned tra = trBase + (unsigned)(cur * 10880);
    u16x4 tv0, tv1, tv2, tv3, tv4;
    asm volatile("ds_read_b64_tr_b16 %0, %1"             : "=v"(tv0) : "v"(tra));
    asm volatile("ds_read_b64_tr_b16 %0, %1 offset:544"  : "=v"(tv1) : "v"(tra));
    asm volatile("ds_read_b64_tr_b16 %0, %1 offset:1088" : "=v"(tv2) : "v"(tra));
    asm volatile("ds_read_b64_tr_b16 %0, %1 offset:1632" : "=v"(tv3) : "v"(tra));
    asm volatile("ds_read_b64_tr_b16 %0, %1 offset:2176" : "=v"(tv4) : "v"(tra));
    asm volatile("s_waitcnt lgkmcnt(0)" ::: "memory");
    __builtin_amdgcn_sched_barrier(0);
#define PVN(n, tvn)                                                              \
    {                                                                            \
      bf16x8 bb = { (short)(tvn)[0], (short)(tvn)[1], (short)(tvn)[2],           \
                    (short)(tvn)[3], 0, 0, 0, 0 };                               \
      ctx[n] = mfma32(PA.v, bb, ctx[n]);                                         \
    }
    PVN(0, tv0) PVN(1, tv1) PVN(2, tv2) PVN(3, tv3) PVN(4, tv4)
#undef PVN

    if (hn) { STAGE_WRITE(nxt); }
    __syncthreads();
  }

  // ---------- epilogue: merge 4 s-quarters, normalize, write ----------
  if (g == 0) {
    mst[hq * 64 + 16 * pp + l15] = mr;
    lst[hq * 64 + 16 * pp + l15] = lr;
  }
  __syncthreads();
  float F;
  {
    const int pi = 16 * pp + l15;
    float M = fmaxf(fmaxf(mst[pi], mst[64 + pi]), fmaxf(mst[128 + pi], mst[192 + pi]));
    F = __expf(mr - M);
  }
  float gg[4];
#pragma unroll
  for (int rr = 0; rr < 4; ++rr) gg[rr] = __shfl(F, 4 * g + rr);
  float* cacc = (float*)smem;  // [64][84]
  for (int qq = 0; qq < 4; ++qq) {
    if (hq == qq) {
#pragma unroll
      for (int n = 0; n < 5; ++n) {
#pragma unroll
        for (int rr = 0; rr < 4; ++rr) {
          const int row = 16 * pp + 4 * g + rr;
          const int col = 16 * n + l15;
          float v = ctx[n][rr] * gg[rr];
          if (qq == 0) cacc[row * 84 + col] = v;
          else         cacc[row * 84 + col] += v;
        }
      }
    }
    __syncthreads();
  }
  {
    const int op = tid >> 4, oc = tid & 15;
    float Mv = fmaxf(fmaxf(mst[op], mst[64 + op]), fmaxf(mst[128 + op], mst[192 + op]));
    float Lv = lst[op] * __expf(mst[op] - Mv) + lst[64 + op] * __expf(mst[64 + op] - Mv)
             + lst[128 + op] * __expf(mst[128 + op] - Mv) + lst[192 + op] * __expf(mst[192 + op] - Mv);
    float inv = 1.0f / Lv;
    float* orow = out + ((size_t)b * NP + op) * ND + oc * 5;
    const float* crow = cacc + op * 84 + oc * 5;
#pragma unroll
    for (int i = 0; i < 5; ++i) orow[i] = crow[i] * inv;
  }
}

extern "C" void kernel_launch(void* const* d_in, const int* in_sizes, int n_in,
                              void* d_out, int out_size, void* d_ws, size_t ws_size,
                              hipStream_t stream) {
  (void)in_sizes; (void)n_in; (void)out_size; (void)d_ws; (void)ws_size;
  const float* enc  = (const float*)d_in[0];
  const float* dec  = (const float*)d_in[1];
  const int*   mask = (const int*)d_in[2];
  const float* W    = (const float*)d_in[3];
  float* out = (float*)d_out;
  DecoderAttention_62989990363717_kernel<<<dim3(NB), dim3(NTHREADS), 0, stream>>>(
      enc, dec, mask, W, out);
}

// Round 7
// 50.841 us; speedup vs baseline: 1.5094x; 1.2761x over previous
//
#include <hip/hip_runtime.h>

#define NB 256
#define NS 2048
#define NP 64
#define ND 80
#define STILE 64
#define NTILE 32            // NS/STILE
#define NTHREADS 1024
#define LOG2E 1.4426950408889634f

typedef __attribute__((ext_vector_type(4))) float f32x4;
typedef __attribute__((ext_vector_type(8))) short bf16x8;
typedef __attribute__((ext_vector_type(4))) unsigned short u16x4;
typedef unsigned short u16;

// ---------------- LDS layout (bytes) ----------------
// ehP  u16[2][4][6][264] @ 0      (25344)  bf16-hi of enc in 16x16 [s][d] row-major
//        regions; region(q,n) = ((buf*4+q)*6+n)*264 u16... (per-buf stride 6336 u16);
//        n=5 region zeroed once (K-pad d=80..95). Stride 264 (=256+8) de-banks writes.
// elP  u16[2][4][6][264] @ 25344 (25344)  bf16 residual, same layout
// mbias f32[2048]        @ 50688 (8192)   0.0 or -3e38 per s (mask preconverted)
// mst  f32[4][64] @ 58880 ; lst f32[4][64] @ 59904 ; modep @ 60928
// prologue overlay: W f32[80][84]@0 ; dec f32[64][84]@26880 ; qtmp f32[64][100]@0
// epilogue overlay: cacc f32[64][84]@0
#define SMEM_BYTES 60944

__device__ __forceinline__ float bft(float f) {
  return __uint_as_float(__float_as_uint(f) & 0xFFFF0000u);
}
__device__ __forceinline__ u16 h16(float f) { return (u16)(__float_as_uint(f) >> 16); }
// packed RNE f32x2 -> bf16x2 (lo16 = cvt(lo), hi16 = cvt(hi)) [T12 recipe]
__device__ __forceinline__ unsigned cvtpk(float lo, float hi) {
  unsigned r;
  asm("v_cvt_pk_bf16_f32 %0, %1, %2" : "=v"(r) : "v"(lo), "v"(hi));
  return r;
}
__device__ __forceinline__ float E2(float x) { return __builtin_amdgcn_exp2f(x); }

// 16x16 K=32 bf16 MFMA. C/D: col=lane&15, row=4*(lane>>4)+r [guide m89/m91].
__device__ __forceinline__ f32x4 mfma32(bf16x8 a, bf16x8 b, f32x4 c) {
  return __builtin_amdgcn_mfma_f32_16x16x32_bf16(a, b, c, 0, 0, 0);
}

__global__ __launch_bounds__(NTHREADS, 4)
void DecoderAttention_62989990363717_kernel(const float* __restrict__ enc,
                                            const float* __restrict__ dec,
                                            const int* __restrict__ maskp,
                                            const float* __restrict__ W,
                                            float* __restrict__ out)
{
  __shared__ __align__(16) char smem[SMEM_BYTES];

  u16* ehP    = (u16*)smem;               // [2][6336]
  u16* elP    = (u16*)(smem + 25344);     // [2][6336]  (= ehP + 12672 u16)
  float* mbias = (float*)(smem + 50688);  // [2048]
  float* mst  = (float*)(smem + 58880);   // [4][64]
  float* lst  = (float*)(smem + 59904);   // [4][64]
  int* modep  = (int*)(smem + 60928);

  const int tid  = (int)threadIdx.x;
  const int lane = tid & 63;
  const int wv   = tid >> 6;    // 0..15
  const int pp   = wv & 3;      // p-block: rows [16*pp, 16*pp+16)
  const int hq   = wv >> 2;     // s-quarter within tile: [16*hq, 16*hq+16)
  const int l15  = lane & 15;
  const int g    = lane >> 4;
  const int b    = (int)blockIdx.x;

  const float* encB = enc + (size_t)b * NS * ND;
  const float* decB = dec + (size_t)b * NP * ND;

  // ---------- prologue: W, dec(scaled) -> LDS; mask->bias; Q ----------
  {
    float* Wl = (float*)smem;            // [80][84]
    float* dl = (float*)(smem + 26880);  // [64][84]
    for (int i = tid; i < 80 * 80; i += NTHREADS) Wl[(i / 80) * 84 + (i % 80)] = W[i];
    for (int i = tid; i < 64 * 80; i += NTHREADS)
      dl[(i / 80) * 84 + (i % 80)] = decB[i] * LOG2E;   // exp2-domain scores
    if (tid == 0) {
      const unsigned* mw = (const unsigned*)maskp;
      int ok = 1;
      for (int i = 0; i < 16; ++i) ok &= (mw[i] <= 1u);
      *modep = ok;   // 1 => int32 mask, 0 => int8 mask
    }
    __syncthreads();
    const int m32 = *modep;
    if (m32) {
      int v0 = maskp[(size_t)b * NS + tid];
      int v1 = maskp[(size_t)b * NS + tid + 1024];
      mbias[tid]        = v0 ? -3.0e38f : 0.0f;
      mbias[tid + 1024] = v1 ? -3.0e38f : 0.0f;
    } else if (tid < 512) {
      unsigned w = ((const unsigned*)maskp)[(size_t)b * (NS / 4) + tid];
      f32x4 bb;
      bb[0] = (w & 255u)         ? -3.0e38f : 0.0f;
      bb[1] = ((w >> 8) & 255u)  ? -3.0e38f : 0.0f;
      bb[2] = ((w >> 16) & 255u) ? -3.0e38f : 0.0f;
      bb[3] = (w >> 24)          ? -3.0e38f : 0.0f;
      *(f32x4*)&mbias[4 * tid] = bb;
    }
    // Q = dec @ W^T in fp32 (512 threads: p = tid&63, e-range = 10*qw)
    float qa[10];
    const int qp = tid & 63, qw = (tid >> 6) & 7;
    if (tid < 512) {
#pragma unroll
      for (int j = 0; j < 10; ++j) qa[j] = 0.f;
      for (int kg = 0; kg < 20; ++kg) {
        f32x4 dv = *(const f32x4*)&dl[qp * 84 + kg * 4];
#pragma unroll
        for (int j = 0; j < 10; ++j) {
          f32x4 wv4 = *(const f32x4*)&Wl[(qw * 10 + j) * 84 + kg * 4];
          qa[j] = fmaf(dv.x, wv4.x, qa[j]);
          qa[j] = fmaf(dv.y, wv4.y, qa[j]);
          qa[j] = fmaf(dv.z, wv4.z, qa[j]);
          qa[j] = fmaf(dv.w, wv4.w, qa[j]);
        }
      }
    }
    __syncthreads();            // Wl/dl reads done
    float* qtmp = (float*)smem; // [64][100], zeros at d=80..95
    if (tid < 512) {
#pragma unroll
      for (int j = 0; j < 10; ++j) qtmp[qp * 100 + qw * 10 + j] = qa[j];
      if (qw == 7) {
#pragma unroll
        for (int z = 0; z < 16; ++z) qtmp[qp * 100 + 80 + z] = 0.f;
      }
    }
    __syncthreads();
  }

  // ---------- Q fragments (persistent, bf16 hi/lo split) ----------
  bf16x8 qb[3], qlb[3];
  {
    const float* qtmp = (const float*)smem;
    const int prow = 16 * pp + l15;
#pragma unroll
    for (int kk = 0; kk < 3; ++kk) {
      const int d0 = kk * 32 + g * 8;
      f32x4 f0 = *(const f32x4*)&qtmp[prow * 100 + d0];
      f32x4 f1 = *(const f32x4*)&qtmp[prow * 100 + d0 + 4];
      float fq[8] = {f0.x, f0.y, f0.z, f0.w, f1.x, f1.y, f1.z, f1.w};
      union { u16 u[8]; bf16x8 v; } H, L;
#pragma unroll
      for (int j = 0; j < 8; ++j) {
        H.u[j] = h16(fq[j]);
        L.u[j] = h16(fq[j] - bft(fq[j]));
      }
      qb[kk] = H.v; qlb[kk] = L.v;
    }
  }
  __syncthreads();   // qtmp dead; staging may overwrite

  // ---------- zero K-pad regions (n=5) once: both arrays, both buffers ----------
  if (tid < 512) {
    const int arr = tid >> 8, buf = (tid >> 7) & 1, q = (tid >> 5) & 3, t = tid & 31;
    u16* p = ehP + arr * 12672 + buf * 6336 + (q * 6 + 5) * 264 + t * 8;
    *(uint4*)p = make_uint4(0u, 0u, 0u, 0u);
  }

  // loader roles: tid<320 stage enc (5 threads/row, 16 f32 each, all-b128 writes)
  const bool ldr = (tid < 320);
  const int srow = tid / 5;                 // 0..63
  const int c    = tid - srow * 5;          // 0..4 (d-block of 16)
  u16* ePWh = ehP + ((srow >> 4) * 6 + c) * 264 + (srow & 15) * 16;
  u16* ePWl = ePWh + 12672;
  const float* gsrc = encB + srow * ND + 16 * c;

#define STAGE_WRITE(bi)                                                          \
  do {                                                                           \
    if (ldr) {                                                                   \
      float fv[16] = {r0.x, r0.y, r0.z, r0.w, r1.x, r1.y, r1.z, r1.w,            \
                      r2.x, r2.y, r2.z, r2.w, r3.x, r3.y, r3.z, r3.w};           \
      unsigned hh[8], ll[8];                                                     \
      _Pragma("unroll")                                                          \
      for (int q = 0; q < 8; ++q) {                                              \
        unsigned h = cvtpk(fv[2*q], fv[2*q+1]);                                  \
        hh[q] = h;                                                               \
        float hlo = __uint_as_float(h << 16);                                    \
        float hhi = __uint_as_float(h & 0xFFFF0000u);                            \
        ll[q] = cvtpk(fv[2*q] - hlo, fv[2*q+1] - hhi);                           \
      }                                                                          \
      u16* a_ = ePWh + (bi) * 6336;                                              \
      u16* b_ = ePWl + (bi) * 6336;                                              \
      *(uint4*)a_       = make_uint4(hh[0], hh[1], hh[2], hh[3]);                \
      *(uint4*)(a_ + 8) = make_uint4(hh[4], hh[5], hh[6], hh[7]);                \
      *(uint4*)b_       = make_uint4(ll[0], ll[1], ll[2], ll[3]);                \
      *(uint4*)(b_ + 8) = make_uint4(ll[4], ll[5], ll[6], ll[7]);                \
    }                                                                            \
  } while (0)

  // ---------- stage tile 0 ----------
  {
    f32x4 r0, r1, r2, r3;
    if (ldr) {
      r0 = *(const f32x4*)gsrc;       r1 = *(const f32x4*)(gsrc + 4);
      r2 = *(const f32x4*)(gsrc + 8); r3 = *(const f32x4*)(gsrc + 12);
    }
    STAGE_WRITE(0);
    __syncthreads();
  }

  // ---------- main loop ----------
  f32x4 ctx[5];
#pragma unroll
  for (int n = 0; n < 5; ++n) ctx[n] = (f32x4){0.f, 0.f, 0.f, 0.f};
  float mr = -3.0e38f, lr = 0.f;   // lr: PER-LANE partial (reduced in epilogue)

  // QK A-fragment base in ehP subtiles: region(hq, 2kk+(g>>1)), pos 16*l15+8*(g&1)
  const int qkOff = (hq * 6 + (g >> 1)) * 264 + 16 * l15 + 8 * (g & 1);
  // tr-read base: region(hq,0) + 8*lane bytes (verified R5/R6 mapping)
  const unsigned trBase = (unsigned)(uintptr_t)ehP + (unsigned)(hq * 3168 + 8 * lane);

  for (int tt = 0; tt < NTILE; ++tt) {
    const int cur = tt & 1, nxt = cur ^ 1;
    const bool hn = (tt + 1 < NTILE);
    f32x4 r0, r1, r2, r3;
    if (hn && ldr) {   // issue next-tile loads early (consumed at STAGE_WRITE)
      const float* src = gsrc + (size_t)(tt + 1) * STILE * ND;
      r0 = *(const f32x4*)src;       r1 = *(const f32x4*)(src + 4);
      r2 = *(const f32x4*)(src + 8); r3 = *(const f32x4*)(src + 12);
    }

    // ---- QK^T (swapped): D'[s][p] = E * Q^T, K=96, 3-term bf16 split ----
    const u16* baseH = ehP + cur * 6336 + qkOff;
    bf16x8 ea[3], ec[3];
#pragma unroll
    for (int kk = 0; kk < 3; ++kk) {
      ea[kk] = *(const bf16x8*)(baseH + kk * 528);
      ec[kk] = *(const bf16x8*)(baseH + 12672 + kk * 528);
    }
    f32x4 a = (f32x4){0.f, 0.f, 0.f, 0.f};
#pragma unroll
    for (int kk = 0; kk < 3; ++kk) {
      a = mfma32(ea[kk], qb[kk], a);
      a = mfma32(ec[kk], qb[kk], a);
      a = mfma32(ea[kk], qlb[kk], a);
    }

    // ---- masked online softmax (exp2 domain), defer-max, per-lane lr ----
    f32x4 bias4 = *(const f32x4*)&mbias[tt * 64 + 16 * hq + 4 * g];
    float sv[4];
#pragma unroll
    for (int rr = 0; rr < 4; ++rr) sv[rr] = a[rr] + bias4[rr];
    float tm = fmaxf(fmaxf(sv[0], sv[1]), fmaxf(sv[2], sv[3]));
    tm = fmaxf(tm, __shfl_xor(tm, 16));
    tm = fmaxf(tm, __shfl_xor(tm, 32));
    const bool need = !__all(tm <= mr + 11.541560f);   // 8 * log2(e)
    if (need) {
      float mn = fmaxf(mr, tm);
      float esc = E2(mr - mn);
      lr *= esc; mr = mn;
      float fr[4];
#pragma unroll
      for (int rr = 0; rr < 4; ++rr) fr[rr] = __shfl(esc, 4 * g + rr);
#pragma unroll
      for (int n = 0; n < 5; ++n) {
#pragma unroll
        for (int rr = 0; rr < 4; ++rr) ctx[n][rr] *= fr[rr];
      }
    }
    float p[4];
#pragma unroll
    for (int rr = 0; rr < 4; ++rr) p[rr] = E2(sv[rr] - mr);
    lr += (p[0] + p[1]) + (p[2] + p[3]);   // per-lane partial, no shfl

    // ---- PV: ctx[p][d] += P[p][s16] * E[s16][d]; B via ds_read_b64_tr_b16 ----
    union { unsigned uu[4]; bf16x8 v; } PA;
    PA.uu[0] = cvtpk(p[0], p[1]); PA.uu[1] = cvtpk(p[2], p[3]);
    PA.uu[2] = 0u; PA.uu[3] = 0u;
    const unsigned tra = trBase + (unsigned)(cur * 12672);
    u16x4 tv0, tv1, tv2, tv3, tv4;
    asm volatile("ds_read_b64_tr_b16 %0, %1"             : "=v"(tv0) : "v"(tra));
    asm volatile("ds_read_b64_tr_b16 %0, %1 offset:528"  : "=v"(tv1) : "v"(tra));
    asm volatile("ds_read_b64_tr_b16 %0, %1 offset:1056" : "=v"(tv2) : "v"(tra));
    asm volatile("ds_read_b64_tr_b16 %0, %1 offset:1584" : "=v"(tv3) : "v"(tra));
    asm volatile("ds_read_b64_tr_b16 %0, %1 offset:2112" : "=v"(tv4) : "v"(tra));
    asm volatile("s_waitcnt lgkmcnt(0)" ::: "memory");
    __builtin_amdgcn_sched_barrier(0);
#define PVN(n, tvn)                                                              \
    {                                                                            \
      bf16x8 bb = { (short)(tvn)[0], (short)(tvn)[1], (short)(tvn)[2],           \
                    (short)(tvn)[3], 0, 0, 0, 0 };                               \
      ctx[n] = mfma32(PA.v, bb, ctx[n]);                                         \
    }
    PVN(0, tv0) PVN(1, tv1) PVN(2, tv2) PVN(3, tv3) PVN(4, tv4)
#undef PVN

    if (hn) { STAGE_WRITE(nxt); }
    __syncthreads();
  }

  // ---------- epilogue: reduce lr, merge 4 s-quarters, normalize, write ----------
  lr += __shfl_xor(lr, 16);
  lr += __shfl_xor(lr, 32);
  if (g == 0) {
    mst[hq * 64 + 16 * pp + l15] = mr;
    lst[hq * 64 + 16 * pp + l15] = lr;
  }
  __syncthreads();
  float F;
  {
    const int pi = 16 * pp + l15;
    float M = fmaxf(fmaxf(mst[pi], mst[64 + pi]), fmaxf(mst[128 + pi], mst[192 + pi]));
    F = E2(mr - M);
  }
  float gg[4];
#pragma unroll
  for (int rr = 0; rr < 4; ++rr) gg[rr] = __shfl(F, 4 * g + rr);
  float* cacc = (float*)smem;  // [64][84]
  for (int qq = 0; qq < 4; ++qq) {
    if (hq == qq) {
#pragma unroll
      for (int n = 0; n < 5; ++n) {
#pragma unroll
        for (int rr = 0; rr < 4; ++rr) {
          const int row = 16 * pp + 4 * g + rr;
          const int col = 16 * n + l15;
          float v = ctx[n][rr] * gg[rr];
          if (qq == 0) cacc[row * 84 + col] = v;
          else         cacc[row * 84 + col] += v;
        }
      }
    }
    __syncthreads();
  }
  {
    const int op = tid >> 4, oc = tid & 15;
    float Mv = fmaxf(fmaxf(mst[op], mst[64 + op]), fmaxf(mst[128 + op], mst[192 + op]));
    float Lv = lst[op] * E2(mst[op] - Mv) + lst[64 + op] * E2(mst[64 + op] - Mv)
             + lst[128 + op] * E2(mst[128 + op] - Mv) + lst[192 + op] * E2(mst[192 + op] - Mv);
    float inv = 1.0f / Lv;
    float* orow = out + ((size_t)b * NP + op) * ND + oc * 5;
    const float* crow = cacc + op * 84 + oc * 5;
#pragma unroll
    for (int i = 0; i < 5; ++i) orow[i] = crow[i] * inv;
  }
}

extern "C" void kernel_launch(void* const* d_in, const int* in_sizes, int n_in,
                              void* d_out, int out_size, void* d_ws, size_t ws_size,
                              hipStream_t stream) {
  (void)in_sizes; (void)n_in; (void)out_size; (void)d_ws; (void)ws_size;
  const float* enc  = (const float*)d_in[0];
  const float* dec  = (const float*)d_in[1];
  const int*   mask = (const int*)d_in[2];
  const float* W    = (const float*)d_in[3];
  float* out = (float*)d_out;
  DecoderAttention_62989990363717_kernel<<<dim3(NB), dim3(NTHREADS), 0, stream>>>(
      enc, dec, mask, W, out);
}

// Round 8
// 44.811 us; speedup vs baseline: 1.7125x; 1.1346x over previous
//
#include <hip/hip_runtime.h>

#define NB 256
#define NS 2048
#define NP 64
#define ND 80
#define STILE 128
#define NTILE 16            // NS/STILE
#define NTHREADS 1024
#define LOG2E 1.4426950408889634f

typedef __attribute__((ext_vector_type(4))) float f32x4;
typedef __attribute__((ext_vector_type(8))) short bf16x8;
typedef __attribute__((ext_vector_type(4))) unsigned short u16x4;
typedef unsigned short u16;

// ---------------- LDS layout (bytes) ----------------
// ehP  u16[2][8][6][264] @ 0      (50688)  bf16-hi of enc, 16x16 [s][d] row-major regions;
//        region(q,n), q = s>>4 (8 quarters of 128-row tile), n = d-block (n=5 = K-pad,
//        zeroed once). Region stride 264 u16 (=528B); per-buf stride 12672 u16.
// elP  u16[2][8][6][264] @ 50688 (50688)  bf16 residual, same layout
// mbias f32[2048]        @ 101376 (8192)  0.0 / -3e38 per s (mask preconverted)
// mst  f32[4][64] @ 109568 ; lst f32[4][64] @ 110592 ; modep @ 111616
// prologue overlay: W f32[80][84]@0 ; dec f32[64][84]@26880 ; qtmp f32[64][100]@0
// epilogue overlay: cacc f32[64][84]@0
#define SMEM_BYTES 111680

__device__ __forceinline__ float bft(float f) {
  return __uint_as_float(__float_as_uint(f) & 0xFFFF0000u);
}
__device__ __forceinline__ u16 h16(float f) { return (u16)(__float_as_uint(f) >> 16); }
// packed RNE f32x2 -> bf16x2 (lo16 = cvt(lo), hi16 = cvt(hi)) [T12 recipe]
__device__ __forceinline__ unsigned cvtpk(float lo, float hi) {
  unsigned r;
  asm("v_cvt_pk_bf16_f32 %0, %1, %2" : "=v"(r) : "v"(lo), "v"(hi));
  return r;
}
__device__ __forceinline__ float E2(float x) { return __builtin_amdgcn_exp2f(x); }

// 16x16 K=32 bf16 MFMA. C/D: col=lane&15, row=4*(lane>>4)+r [guide m89/m91].
// A and B share the (lane-group g, reg-slot j) -> k=8g+j map; any fixed k->s
// permutation is valid as long as A and B use the same one (verified R2-R7).
__device__ __forceinline__ f32x4 mfma32(bf16x8 a, bf16x8 b, f32x4 c) {
  return __builtin_amdgcn_mfma_f32_16x16x32_bf16(a, b, c, 0, 0, 0);
}

__global__ __launch_bounds__(NTHREADS, 4)
void DecoderAttention_62989990363717_kernel(const float* __restrict__ enc,
                                            const float* __restrict__ dec,
                                            const int* __restrict__ maskp,
                                            const float* __restrict__ W,
                                            float* __restrict__ out)
{
  __shared__ __align__(16) char smem[SMEM_BYTES];

  u16* ehP    = (u16*)smem;               // [2][12672]
  u16* elP    = (u16*)(smem + 50688);     // [2][12672] (= ehP + 25344 u16)
  float* mbias = (float*)(smem + 101376); // [2048]
  float* mst  = (float*)(smem + 109568);  // [4][64]
  float* lst  = (float*)(smem + 110592);  // [4][64]
  int* modep  = (int*)(smem + 111616);

  const int tid  = (int)threadIdx.x;
  const int lane = tid & 63;
  const int wv   = tid >> 6;    // 0..15
  const int pp   = wv & 3;      // p-block: rows [16*pp, 16*pp+16)
  const int sq   = wv >> 2;     // 32-row s-slice within tile: quarters {2sq, 2sq+1}
  const int l15  = lane & 15;
  const int g    = lane >> 4;
  const int b    = (int)blockIdx.x;

  const float* encB = enc + (size_t)b * NS * ND;
  const float* decB = dec + (size_t)b * NP * ND;

  // ---------- prologue: W, dec(scaled) -> LDS; mask->bias; Q ----------
  {
    float* Wl = (float*)smem;            // [80][84]
    float* dl = (float*)(smem + 26880);  // [64][84]
    for (int i = tid; i < 80 * 80; i += NTHREADS) Wl[(i / 80) * 84 + (i % 80)] = W[i];
    for (int i = tid; i < 64 * 80; i += NTHREADS)
      dl[(i / 80) * 84 + (i % 80)] = decB[i] * LOG2E;   // exp2-domain scores
    if (tid == 0) {
      const unsigned* mw = (const unsigned*)maskp;
      int ok = 1;
      for (int i = 0; i < 16; ++i) ok &= (mw[i] <= 1u);
      *modep = ok;   // 1 => int32 mask, 0 => int8 mask
    }
    __syncthreads();
    const int m32 = *modep;
    if (m32) {
      int v0 = maskp[(size_t)b * NS + tid];
      int v1 = maskp[(size_t)b * NS + tid + 1024];
      mbias[tid]        = v0 ? -3.0e38f : 0.0f;
      mbias[tid + 1024] = v1 ? -3.0e38f : 0.0f;
    } else if (tid < 512) {
      unsigned w = ((const unsigned*)maskp)[(size_t)b * (NS / 4) + tid];
      f32x4 bb;
      bb[0] = (w & 255u)         ? -3.0e38f : 0.0f;
      bb[1] = ((w >> 8) & 255u)  ? -3.0e38f : 0.0f;
      bb[2] = ((w >> 16) & 255u) ? -3.0e38f : 0.0f;
      bb[3] = (w >> 24)          ? -3.0e38f : 0.0f;
      *(f32x4*)&mbias[4 * tid] = bb;
    }
    // Q = dec @ W^T in fp32 (all 1024 threads: p = tid&63, e-range = 5*qw)
    float qa[5];
    const int qp = tid & 63, qw = tid >> 6;   // qw 0..15
#pragma unroll
    for (int j = 0; j < 5; ++j) qa[j] = 0.f;
    for (int kg = 0; kg < 20; ++kg) {
      f32x4 dv = *(const f32x4*)&dl[qp * 84 + kg * 4];
#pragma unroll
      for (int j = 0; j < 5; ++j) {
        f32x4 wv4 = *(const f32x4*)&Wl[(qw * 5 + j) * 84 + kg * 4];
        qa[j] = fmaf(dv.x, wv4.x, qa[j]);
        qa[j] = fmaf(dv.y, wv4.y, qa[j]);
        qa[j] = fmaf(dv.z, wv4.z, qa[j]);
        qa[j] = fmaf(dv.w, wv4.w, qa[j]);
      }
    }
    __syncthreads();            // Wl/dl reads done
    float* qtmp = (float*)smem; // [64][100], zeros at d=80..95
#pragma unroll
    for (int j = 0; j < 5; ++j) qtmp[qp * 100 + qw * 5 + j] = qa[j];
    if (qw == 15) {
#pragma unroll
      for (int z = 0; z < 16; ++z) qtmp[qp * 100 + 80 + z] = 0.f;
    }
    __syncthreads();
  }

  // ---------- Q fragments (persistent, bf16 hi/lo split) ----------
  bf16x8 qb[3], qlb[3];
  {
    const float* qtmp = (const float*)smem;
    const int prow = 16 * pp + l15;
#pragma unroll
    for (int kk = 0; kk < 3; ++kk) {
      const int d0 = kk * 32 + g * 8;
      f32x4 f0 = *(const f32x4*)&qtmp[prow * 100 + d0];
      f32x4 f1 = *(const f32x4*)&qtmp[prow * 100 + d0 + 4];
      float fq[8] = {f0.x, f0.y, f0.z, f0.w, f1.x, f1.y, f1.z, f1.w};
      union { u16 u[8]; bf16x8 v; } H, L;
#pragma unroll
      for (int j = 0; j < 8; ++j) {
        H.u[j] = h16(fq[j]);
        L.u[j] = h16(fq[j] - bft(fq[j]));
      }
      qb[kk] = H.v; qlb[kk] = L.v;
    }
  }
  __syncthreads();   // qtmp dead; staging may overwrite

  // ---------- zero K-pad regions (n=5) once: both arrays, bufs, 8 quarters ----------
  if (tid < 512) {
    const int arr = tid >> 8, buf = (tid >> 7) & 1, q = (tid >> 4) & 7, row = tid & 15;
    u16* p = ehP + arr * 25344 + buf * 12672 + (q * 6 + 5) * 264 + row * 16;
    *(uint4*)p = make_uint4(0u, 0u, 0u, 0u);
    *(uint4*)(p + 8) = make_uint4(0u, 0u, 0u, 0u);
  }

  // loader roles: tid<640 stage enc (5 threads/row, 16 f32 each, all-b128 writes)
  const bool ldr = (tid < 640);
  const int srow = tid / 5;                 // 0..127
  const int c    = tid - srow * 5;          // 0..4 (d-block of 16)
  u16* ePWh = ehP + ((srow >> 4) * 6 + c) * 264 + (srow & 15) * 16;
  u16* ePWl = ePWh + 25344;
  const float* gsrc = encB + srow * ND + 16 * c;

#define STAGE_WRITE(bi)                                                          \
  do {                                                                           \
    if (ldr) {                                                                   \
      float fv[16] = {r0.x, r0.y, r0.z, r0.w, r1.x, r1.y, r1.z, r1.w,            \
                      r2.x, r2.y, r2.z, r2.w, r3.x, r3.y, r3.z, r3.w};           \
      unsigned hh[8], ll[8];                                                     \
      _Pragma("unroll")                                                          \
      for (int q = 0; q < 8; ++q) {                                              \
        unsigned h = cvtpk(fv[2*q], fv[2*q+1]);                                  \
        hh[q] = h;                                                               \
        float hlo = __uint_as_float(h << 16);                                    \
        float hhi = __uint_as_float(h & 0xFFFF0000u);                            \
        ll[q] = cvtpk(fv[2*q] - hlo, fv[2*q+1] - hhi);                           \
      }                                                                          \
      u16* a_ = ePWh + (bi) * 12672;                                             \
      u16* b_ = ePWl + (bi) * 12672;                                             \
      *(uint4*)a_       = make_uint4(hh[0], hh[1], hh[2], hh[3]);                \
      *(uint4*)(a_ + 8) = make_uint4(hh[4], hh[5], hh[6], hh[7]);                \
      *(uint4*)b_       = make_uint4(ll[0], ll[1], ll[2], ll[3]);                \
      *(uint4*)(b_ + 8) = make_uint4(ll[4], ll[5], ll[6], ll[7]);                \
    }                                                                            \
  } while (0)

  // ---------- stage tile 0 ----------
  {
    f32x4 r0, r1, r2, r3;
    if (ldr) {
      r0 = *(const f32x4*)gsrc;       r1 = *(const f32x4*)(gsrc + 4);
      r2 = *(const f32x4*)(gsrc + 8); r3 = *(const f32x4*)(gsrc + 12);
    }
    STAGE_WRITE(0);
    __syncthreads();
  }

  // ---------- main loop ----------
  f32x4 ctx[5];
#pragma unroll
  for (int n = 0; n < 5; ++n) ctx[n] = (f32x4){0.f, 0.f, 0.f, 0.f};
  float mr = -3.0e38f, lr = 0.f;   // lr: per-lane partial (reduced in epilogue)

  // QK A-frag base (u16 idx): region(2sq+b, (g>>1)+2kk) + 16*l15 + 8*(g&1)
  const int qkOff = (2 * sq) * 1584 + (g >> 1) * 264 + 16 * l15 + 8 * (g & 1);
  // PV tr-read base (bytes): region(2sq, n) + 8*lane;  blk1 = +3168B, n-step = 528B
  const unsigned trBase = (unsigned)(uintptr_t)ehP + (unsigned)(sq * 6336 + 8 * lane);

  for (int tt = 0; tt < NTILE; ++tt) {
    const int cur = tt & 1, nxt = cur ^ 1;
    const bool hn = (tt + 1 < NTILE);
    f32x4 r0, r1, r2, r3;
    if (hn && ldr) {   // issue next-tile loads early (consumed at STAGE_WRITE)
      const float* src = gsrc + (size_t)(tt + 1) * STILE * ND;
      r0 = *(const f32x4*)src;       r1 = *(const f32x4*)(src + 4);
      r2 = *(const f32x4*)(src + 8); r3 = *(const f32x4*)(src + 12);
    }

    // ---- QK^T (swapped): two 16-row blocks, K=96, 3-term bf16 split ----
    f32x4 a0 = (f32x4){0.f, 0.f, 0.f, 0.f}, a1 = (f32x4){0.f, 0.f, 0.f, 0.f};
#pragma unroll
    for (int bb2 = 0; bb2 < 2; ++bb2) {
      const u16* baseH = ehP + cur * 12672 + qkOff + bb2 * 1584;
      bf16x8 ea[3], ec[3];
#pragma unroll
      for (int kk = 0; kk < 3; ++kk) {
        ea[kk] = *(const bf16x8*)(baseH + kk * 528);
        ec[kk] = *(const bf16x8*)(baseH + 25344 + kk * 528);
      }
      if (bb2 == 0) {
#pragma unroll
        for (int kk = 0; kk < 3; ++kk) {
          a0 = mfma32(ea[kk], qb[kk], a0);
          a0 = mfma32(ec[kk], qb[kk], a0);
          a0 = mfma32(ea[kk], qlb[kk], a0);
        }
      } else {
#pragma unroll
        for (int kk = 0; kk < 3; ++kk) {
          a1 = mfma32(ea[kk], qb[kk], a1);
          a1 = mfma32(ec[kk], qb[kk], a1);
          a1 = mfma32(ea[kk], qlb[kk], a1);
        }
      }
    }

    // ---- masked online softmax over 32 rows (exp2 domain), defer-max ----
    const int mb0 = tt * 128 + 32 * sq + 4 * g;
    f32x4 bias0 = *(const f32x4*)&mbias[mb0];
    f32x4 bias1 = *(const f32x4*)&mbias[mb0 + 16];
    float sv0[4], sv1[4];
#pragma unroll
    for (int rr = 0; rr < 4; ++rr) {
      sv0[rr] = a0[rr] + bias0[rr];
      sv1[rr] = a1[rr] + bias1[rr];
    }
    float tm = fmaxf(fmaxf(fmaxf(sv0[0], sv0[1]), fmaxf(sv0[2], sv0[3])),
                     fmaxf(fmaxf(sv1[0], sv1[1]), fmaxf(sv1[2], sv1[3])));
    tm = fmaxf(tm, __shfl_xor(tm, 16));
    tm = fmaxf(tm, __shfl_xor(tm, 32));
    const bool need = !__all(tm <= mr + 11.541560f);   // 8 * log2(e)
    if (need) {
      float mn = fmaxf(mr, tm);
      float esc = E2(mr - mn);
      lr *= esc; mr = mn;
      float fr[4];
#pragma unroll
      for (int rr = 0; rr < 4; ++rr) fr[rr] = __shfl(esc, 4 * g + rr);
#pragma unroll
      for (int n = 0; n < 5; ++n) {
#pragma unroll
        for (int rr = 0; rr < 4; ++rr) ctx[n][rr] *= fr[rr];
      }
    }
    float p0[4], p1[4];
#pragma unroll
    for (int rr = 0; rr < 4; ++rr) {
      p0[rr] = E2(sv0[rr] - mr);
      p1[rr] = E2(sv1[rr] - mr);
    }
    lr += ((p0[0] + p0[1]) + (p0[2] + p0[3])) + ((p1[0] + p1[1]) + (p1[2] + p1[3]));

    // ---- PV: full-K=32 MFMA. A slots: j=0..3 <- blk0 rows 4g+j (c0,c1),
    //      j=4..7 <- blk1 rows 4g+j (c2,c3). B slots: tr-read(blk b, d-block n)
    //      delivers E_blkb[4g+j][16n+l15] into slots 4b+j — same k->s map. ----
    union { unsigned uu[4]; bf16x8 v; } PA;
    PA.uu[0] = cvtpk(p0[0], p0[1]); PA.uu[1] = cvtpk(p0[2], p0[3]);
    PA.uu[2] = cvtpk(p1[0], p1[1]); PA.uu[3] = cvtpk(p1[2], p1[3]);
    const unsigned tra = trBase + (unsigned)(cur * 25344);
    {
      u16x4 ta0, tb0, ta1, tb1, ta2, tb2;
      asm volatile("ds_read_b64_tr_b16 %0, %1"             : "=v"(ta0) : "v"(tra));
      asm volatile("ds_read_b64_tr_b16 %0, %1 offset:3168" : "=v"(tb0) : "v"(tra));
      asm volatile("ds_read_b64_tr_b16 %0, %1 offset:528"  : "=v"(ta1) : "v"(tra));
      asm volatile("ds_read_b64_tr_b16 %0, %1 offset:3696" : "=v"(tb1) : "v"(tra));
      asm volatile("ds_read_b64_tr_b16 %0, %1 offset:1056" : "=v"(ta2) : "v"(tra));
      asm volatile("ds_read_b64_tr_b16 %0, %1 offset:4224" : "=v"(tb2) : "v"(tra));
      asm volatile("s_waitcnt lgkmcnt(0)" ::: "memory");
      __builtin_amdgcn_sched_barrier(0);
      bf16x8 b0 = {(short)ta0[0], (short)ta0[1], (short)ta0[2], (short)ta0[3],
                   (short)tb0[0], (short)tb0[1], (short)tb0[2], (short)tb0[3]};
      ctx[0] = mfma32(PA.v, b0, ctx[0]);
      bf16x8 b1 = {(short)ta1[0], (short)ta1[1], (short)ta1[2], (short)ta1[3],
                   (short)tb1[0], (short)tb1[1], (short)tb1[2], (short)tb1[3]};
      ctx[1] = mfma32(PA.v, b1, ctx[1]);
      bf16x8 b2 = {(short)ta2[0], (short)ta2[1], (short)ta2[2], (short)ta2[3],
                   (short)tb2[0], (short)tb2[1], (short)tb2[2], (short)tb2[3]};
      ctx[2] = mfma32(PA.v, b2, ctx[2]);
    }
    {
      u16x4 ta3, tb3, ta4, tb4;
      asm volatile("ds_read_b64_tr_b16 %0, %1 offset:1584" : "=v"(ta3) : "v"(tra));
      asm volatile("ds_read_b64_tr_b16 %0, %1 offset:4752" : "=v"(tb3) : "v"(tra));
      asm volatile("ds_read_b64_tr_b16 %0, %1 offset:2112" : "=v"(ta4) : "v"(tra));
      asm volatile("ds_read_b64_tr_b16 %0, %1 offset:5280" : "=v"(tb4) : "v"(tra));
      asm volatile("s_waitcnt lgkmcnt(0)" ::: "memory");
      __builtin_amdgcn_sched_barrier(0);
      bf16x8 b3 = {(short)ta3[0], (short)ta3[1], (short)ta3[2], (short)ta3[3],
                   (short)tb3[0], (short)tb3[1], (short)tb3[2], (short)tb3[3]};
      ctx[3] = mfma32(PA.v, b3, ctx[3]);
      bf16x8 b4 = {(short)ta4[0], (short)ta4[1], (short)ta4[2], (short)ta4[3],
                   (short)tb4[0], (short)tb4[1], (short)tb4[2], (short)tb4[3]};
      ctx[4] = mfma32(PA.v, b4, ctx[4]);
    }

    if (hn) { STAGE_WRITE(nxt); }
    __syncthreads();
  }

  // ---------- epilogue: reduce lr, merge 4 s-slices, normalize, write ----------
  lr += __shfl_xor(lr, 16);
  lr += __shfl_xor(lr, 32);
  if (g == 0) {
    mst[sq * 64 + 16 * pp + l15] = mr;
    lst[sq * 64 + 16 * pp + l15] = lr;
  }
  __syncthreads();
  float F;
  {
    const int pi = 16 * pp + l15;
    float M = fmaxf(fmaxf(mst[pi], mst[64 + pi]), fmaxf(mst[128 + pi], mst[192 + pi]));
    F = E2(mr - M);
  }
  float gg[4];
#pragma unroll
  for (int rr = 0; rr < 4; ++rr) gg[rr] = __shfl(F, 4 * g + rr);
  float* cacc = (float*)smem;  // [64][84]
  for (int qq = 0; qq < 4; ++qq) {
    if (sq == qq) {
#pragma unroll
      for (int n = 0; n < 5; ++n) {
#pragma unroll
        for (int rr = 0; rr < 4; ++rr) {
          const int row = 16 * pp + 4 * g + rr;
          const int col = 16 * n + l15;
          float v = ctx[n][rr] * gg[rr];
          if (qq == 0) cacc[row * 84 + col] = v;
          else         cacc[row * 84 + col] += v;
        }
      }
    }
    __syncthreads();
  }
  {
    const int op = tid >> 4, oc = tid & 15;
    float Mv = fmaxf(fmaxf(mst[op], mst[64 + op]), fmaxf(mst[128 + op], mst[192 + op]));
    float Lv = lst[op] * E2(mst[op] - Mv) + lst[64 + op] * E2(mst[64 + op] - Mv)
             + lst[128 + op] * E2(mst[128 + op] - Mv) + lst[192 + op] * E2(mst[192 + op] - Mv);
    float inv = 1.0f / Lv;
    float* orow = out + ((size_t)b * NP + op) * ND + oc * 5;
    const float* crow = cacc + op * 84 + oc * 5;
#pragma unroll
    for (int i = 0; i < 5; ++i) orow[i] = crow[i] * inv;
  }
}

extern "C" void kernel_launch(void* const* d_in, const int* in_sizes, int n_in,
                              void* d_out, int out_size, void* d_ws, size_t ws_size,
                              hipStream_t stream) {
  (void)in_sizes; (void)n_in; (void)out_size; (void)d_ws; (void)ws_size;
  const float* enc  = (const float*)d_in[0];
  const float* dec  = (const float*)d_in[1];
  const int*   mask = (const int*)d_in[2];
  const float* W    = (const float*)d_in[3];
  float* out = (float*)d_out;
  DecoderAttention_62989990363717_kernel<<<dim3(NB), dim3(NTHREADS), 0, stream>>>(
      enc, dec, mask, W, out);
}

// Round 10
// 40.491 us; speedup vs baseline: 1.8952x; 1.1067x over previous
//
#include <hip/hip_runtime.h>

#define NB 256
#define NS 2048
#define NP 64
#define ND 80
#define STILE 128
#define NTILE 16            // NS/STILE
#define NTHREADS 1024
#define LOG2E 1.4426950408889634f

typedef __attribute__((ext_vector_type(4))) float f32x4;
typedef __attribute__((ext_vector_type(2))) __fp16 fp16x2;
typedef __attribute__((ext_vector_type(8))) _Float16 f16x8;
typedef __attribute__((ext_vector_type(4))) unsigned short u16x4;
typedef unsigned short u16;

// ---------------- LDS layout (bytes) ----------------
// ehP  u16[2][8][6][264] @ 0     (50688)  f16 enc, 16x16 [s][d] row-major regions;
//        region(q,n), q = s>>4 (8 quarters of 128-row tile), n = d-block (n=5 = K-pad,
//        zeroed once). Region stride 264 u16 (=528B); per-buf stride 12672 u16.
// mbias f32[2048]        @ 50688 (8192)   0.0 / -3e38 per s (mask preconverted)
// mst  f32[4][64] @ 58880 ; lst f32[4][64] @ 59904 ; modep @ 60928
// prologue overlay: W f32[80][84]@0 ; dec f32[64][84]@26880 (ends 48384 < 50688)
//                   qtmp f32[64][100]@0
// epilogue overlay: cacc f32[64][84]@0
#define SMEM_BYTES 60944

__device__ __forceinline__ float E2(float x) { return __builtin_amdgcn_exp2f(x); }
// f32x2 -> f16x2 (RTZ, single instr v_cvt_pkrtz_f16_f32)
__device__ __forceinline__ unsigned pkh(float lo, float hi) {
  union { fp16x2 h; unsigned u; } cv;
  cv.h = __builtin_amdgcn_cvt_pkrtz(lo, hi);
  return cv.u;
}

// 16x16 K=32 f16 MFMA. C/D: col=lane&15, row=4*(lane>>4)+r (dtype-independent,
// guide m89/m121). A and B share the (lane-group g, reg-slot j) -> k=8g+j map;
// any fixed k->s permutation is valid if A and B use the same one (verified R2-R8).
__device__ __forceinline__ f32x4 mfma16f(f16x8 a, f16x8 b, f32x4 c) {
  return __builtin_amdgcn_mfma_f32_16x16x32_f16(a, b, c, 0, 0, 0);
}

__global__ __launch_bounds__(NTHREADS, 4)
void DecoderAttention_62989990363717_kernel(const float* __restrict__ enc,
                                            const float* __restrict__ dec,
                                            const int* __restrict__ maskp,
                                            const float* __restrict__ W,
                                            float* __restrict__ out)
{
  __shared__ __align__(16) char smem[SMEM_BYTES];

  u16* ehP    = (u16*)smem;               // [2][12672]
  float* mbias = (float*)(smem + 50688);  // [2048]
  float* mst  = (float*)(smem + 58880);   // [4][64]
  float* lst  = (float*)(smem + 59904);   // [4][64]
  int* modep  = (int*)(smem + 60928);

  const int tid  = (int)threadIdx.x;
  const int lane = tid & 63;
  const int wv   = tid >> 6;    // 0..15
  const int pp   = wv & 3;      // p-block: rows [16*pp, 16*pp+16)
  const int sq   = wv >> 2;     // 32-row s-slice within tile: quarters {2sq, 2sq+1}
  const int l15  = lane & 15;
  const int g    = lane >> 4;
  const int b    = (int)blockIdx.x;

  const float* encB = enc + (size_t)b * NS * ND;
  const float* decB = dec + (size_t)b * NP * ND;

  // ---------- prologue: W, dec(scaled) -> LDS; mask->bias; Q ----------
  {
    float* Wl = (float*)smem;            // [80][84]
    float* dl = (float*)(smem + 26880);  // [64][84]
    for (int i = tid; i < 80 * 80; i += NTHREADS) Wl[(i / 80) * 84 + (i % 80)] = W[i];
    for (int i = tid; i < 64 * 80; i += NTHREADS)
      dl[(i / 80) * 84 + (i % 80)] = decB[i] * LOG2E;   // exp2-domain scores
    if (tid == 0) {
      const unsigned* mw = (const unsigned*)maskp;
      int ok = 1;
      for (int i = 0; i < 16; ++i) ok &= (mw[i] <= 1u);
      *modep = ok;   // 1 => int32 mask, 0 => int8 mask
    }
    __syncthreads();
    const int m32 = *modep;
    if (m32) {
      int v0 = maskp[(size_t)b * NS + tid];
      int v1 = maskp[(size_t)b * NS + tid + 1024];
      mbias[tid]        = v0 ? -3.0e38f : 0.0f;
      mbias[tid + 1024] = v1 ? -3.0e38f : 0.0f;
    } else if (tid < 512) {
      unsigned w = ((const unsigned*)maskp)[(size_t)b * (NS / 4) + tid];
      f32x4 bb;
      bb[0] = (w & 255u)         ? -3.0e38f : 0.0f;
      bb[1] = ((w >> 8) & 255u)  ? -3.0e38f : 0.0f;
      bb[2] = ((w >> 16) & 255u) ? -3.0e38f : 0.0f;
      bb[3] = (w >> 24)          ? -3.0e38f : 0.0f;
      *(f32x4*)&mbias[4 * tid] = bb;
    }
    // Q = dec @ W^T in fp32 (all 1024 threads: p = tid&63, e-range = 5*qw)
    float qa[5];
    const int qp = tid & 63, qw = tid >> 6;   // qw 0..15
#pragma unroll
    for (int j = 0; j < 5; ++j) qa[j] = 0.f;
    for (int kg = 0; kg < 20; ++kg) {
      f32x4 dv = *(const f32x4*)&dl[qp * 84 + kg * 4];
#pragma unroll
      for (int j = 0; j < 5; ++j) {
        f32x4 wv4 = *(const f32x4*)&Wl[(qw * 5 + j) * 84 + kg * 4];
        qa[j] = fmaf(dv.x, wv4.x, qa[j]);
        qa[j] = fmaf(dv.y, wv4.y, qa[j]);
        qa[j] = fmaf(dv.z, wv4.z, qa[j]);
        qa[j] = fmaf(dv.w, wv4.w, qa[j]);
      }
    }
    __syncthreads();            // Wl/dl reads done
    float* qtmp = (float*)smem; // [64][100], zeros at d=80..95
#pragma unroll
    for (int j = 0; j < 5; ++j) qtmp[qp * 100 + qw * 5 + j] = qa[j];
    if (qw == 15) {
#pragma unroll
      for (int z = 0; z < 16; ++z) qtmp[qp * 100 + 80 + z] = 0.f;
    }
    __syncthreads();
  }

  // ---------- Q fragments (persistent, f16 hi/lo split, RNE) ----------
  f16x8 qb[3], qlb[3];
  {
    const float* qtmp = (const float*)smem;
    const int prow = 16 * pp + l15;
#pragma unroll
    for (int kk = 0; kk < 3; ++kk) {
      const int d0 = kk * 32 + g * 8;
      f32x4 f0 = *(const f32x4*)&qtmp[prow * 100 + d0];
      f32x4 f1 = *(const f32x4*)&qtmp[prow * 100 + d0 + 4];
      float fq[8] = {f0.x, f0.y, f0.z, f0.w, f1.x, f1.y, f1.z, f1.w};
      union { _Float16 h[8]; f16x8 v; } H, L;
#pragma unroll
      for (int j = 0; j < 8; ++j) {
        _Float16 hh = (_Float16)fq[j];          // RNE
        H.h[j] = hh;
        L.h[j] = (_Float16)(fq[j] - (float)hh); // residual ~2^-11
      }
      qb[kk] = H.v; qlb[kk] = L.v;
    }
  }
  __syncthreads();   // qtmp dead; staging may overwrite

  // ---------- zero K-pad regions (n=5) once: both buffers, 8 quarters ----------
  if (tid < 256) {
    const int buf = tid >> 7, q = (tid >> 4) & 7, row = tid & 15;
    u16* p = ehP + buf * 12672 + (q * 6 + 5) * 264 + row * 16;
    *(uint4*)p = make_uint4(0u, 0u, 0u, 0u);
    *(uint4*)(p + 8) = make_uint4(0u, 0u, 0u, 0u);
  }

  // loader roles: tid<640 stage enc (5 threads/row, 16 f32 each, all-b128 writes)
  const bool ldr = (tid < 640);
  const int srow = tid / 5;                 // 0..127
  const int c    = tid - srow * 5;          // 0..4 (d-block of 16)
  u16* ePW = ehP + ((srow >> 4) * 6 + c) * 264 + (srow & 15) * 16;
  const float* gsrc = encB + srow * ND + 16 * c;

#define STAGE_WRITE(bi)                                                          \
  do {                                                                           \
    if (ldr) {                                                                   \
      float fv[16] = {r0.x, r0.y, r0.z, r0.w, r1.x, r1.y, r1.z, r1.w,            \
                      r2.x, r2.y, r2.z, r2.w, r3.x, r3.y, r3.z, r3.w};           \
      unsigned hh[8];                                                            \
      _Pragma("unroll")                                                          \
      for (int q = 0; q < 8; ++q) hh[q] = pkh(fv[2*q], fv[2*q+1]);               \
      u16* a_ = ePW + (bi) * 12672;                                              \
      *(uint4*)a_       = make_uint4(hh[0], hh[1], hh[2], hh[3]);                \
      *(uint4*)(a_ + 8) = make_uint4(hh[4], hh[5], hh[6], hh[7]);                \
    }                                                                            \
  } while (0)

  // ---------- stage tile 0 ----------
  {
    f32x4 r0, r1, r2, r3;
    if (ldr) {
      r0 = *(const f32x4*)gsrc;       r1 = *(const f32x4*)(gsrc + 4);
      r2 = *(const f32x4*)(gsrc + 8); r3 = *(const f32x4*)(gsrc + 12);
    }
    STAGE_WRITE(0);
    __syncthreads();
  }

  // ---------- main loop ----------
  f32x4 ctx[5];
#pragma unroll
  for (int n = 0; n < 5; ++n) ctx[n] = (f32x4){0.f, 0.f, 0.f, 0.f};
  float mr = -3.0e38f, lr = 0.f;   // lr: per-lane partial (reduced in epilogue)

  // QK A-frag base (u16 idx): region(2sq+blk, (g>>1)+2kk) + 16*l15 + 8*(g&1)
  //   -> element d = 32kk + 8g + j  (matches qb slot map)
  const int qkOff = (2 * sq) * 1584 + (g >> 1) * 264 + 16 * l15 + 8 * (g & 1);
  // PV tr-read base (bytes): region(2sq, n) + 8*lane; blk1 = +3168B, n-step = 528B
  const unsigned trBase = (unsigned)(uintptr_t)ehP + (unsigned)(sq * 6336 + 8 * lane);

  for (int tt = 0; tt < NTILE; ++tt) {
    const int cur = tt & 1, nxt = cur ^ 1;
    const bool hn = (tt + 1 < NTILE);
    f32x4 r0, r1, r2, r3;
    if (hn && ldr) {   // issue next-tile loads early (consumed at STAGE_WRITE)
      const float* src = gsrc + (size_t)(tt + 1) * STILE * ND;
      r0 = *(const f32x4*)src;       r1 = *(const f32x4*)(src + 4);
      r2 = *(const f32x4*)(src + 8); r3 = *(const f32x4*)(src + 12);
    }

    // ---- QK^T (swapped): two 16-row blocks, K=96, f16 2-term Q split ----
    f32x4 a0 = (f32x4){0.f, 0.f, 0.f, 0.f}, a1 = (f32x4){0.f, 0.f, 0.f, 0.f};
    {
      const u16* baseH0 = ehP + cur * 12672 + qkOff;
      const u16* baseH1 = baseH0 + 1584;
      f16x8 e0[3], e1[3];
#pragma unroll
      for (int kk = 0; kk < 3; ++kk) {
        e0[kk] = *(const f16x8*)(const void*)(baseH0 + kk * 528);
        e1[kk] = *(const f16x8*)(const void*)(baseH1 + kk * 528);
      }
#pragma unroll
      for (int kk = 0; kk < 3; ++kk) {
        a0 = mfma16f(e0[kk], qb[kk], a0);
        a1 = mfma16f(e1[kk], qb[kk], a1);
        a0 = mfma16f(e0[kk], qlb[kk], a0);
        a1 = mfma16f(e1[kk], qlb[kk], a1);
      }
    }

    // ---- masked online softmax over 32 rows (exp2 domain), defer-max ----
    const int mb0 = tt * 128 + 32 * sq + 4 * g;
    f32x4 bias0 = *(const f32x4*)&mbias[mb0];
    f32x4 bias1 = *(const f32x4*)&mbias[mb0 + 16];
    float sv0[4], sv1[4];
#pragma unroll
    for (int rr = 0; rr < 4; ++rr) {
      sv0[rr] = a0[rr] + bias0[rr];
      sv1[rr] = a1[rr] + bias1[rr];
    }
    float tm = fmaxf(fmaxf(fmaxf(sv0[0], sv0[1]), fmaxf(sv0[2], sv0[3])),
                     fmaxf(fmaxf(sv1[0], sv1[1]), fmaxf(sv1[2], sv1[3])));
    tm = fmaxf(tm, __shfl_xor(tm, 16));
    tm = fmaxf(tm, __shfl_xor(tm, 32));
    const bool need = !__all(tm <= mr + 11.541560f);   // 8 * log2(e)
    if (need) {
      float mn = fmaxf(mr, tm);
      float esc = E2(mr - mn);
      lr *= esc; mr = mn;
      float fr[4];
#pragma unroll
      for (int rr = 0; rr < 4; ++rr) fr[rr] = __shfl(esc, 4 * g + rr);
#pragma unroll
      for (int n = 0; n < 5; ++n) {
#pragma unroll
        for (int rr = 0; rr < 4; ++rr) ctx[n][rr] *= fr[rr];
      }
    }
    float p0[4], p1[4];
#pragma unroll
    for (int rr = 0; rr < 4; ++rr) {
      p0[rr] = E2(sv0[rr] - mr);
      p1[rr] = E2(sv1[rr] - mr);
    }
    lr += ((p0[0] + p0[1]) + (p0[2] + p0[3])) + ((p1[0] + p1[1]) + (p1[2] + p1[3]));

    // ---- PV: full-K=32 MFMA. A slots: j=0..3 <- blk0 rows 4g+j,
    //      j=4..7 <- blk1 rows 4g+j. B: tr-read(blk, n) delivers
    //      E_blk[4g+j][16n+l15] into slots 4*blk+j — same k->s map. ----
    union { unsigned uu[4]; f16x8 v; } PA;
    PA.uu[0] = pkh(p0[0], p0[1]); PA.uu[1] = pkh(p0[2], p0[3]);
    PA.uu[2] = pkh(p1[0], p1[1]); PA.uu[3] = pkh(p1[2], p1[3]);
    const unsigned tra = trBase + (unsigned)(cur * 25344);
    {
      u16x4 ta0, tb0, ta1, tb1, ta2, tb2;
      asm volatile("ds_read_b64_tr_b16 %0, %1"             : "=v"(ta0) : "v"(tra));
      asm volatile("ds_read_b64_tr_b16 %0, %1 offset:3168" : "=v"(tb0) : "v"(tra));
      asm volatile("ds_read_b64_tr_b16 %0, %1 offset:528"  : "=v"(ta1) : "v"(tra));
      asm volatile("ds_read_b64_tr_b16 %0, %1 offset:3696" : "=v"(tb1) : "v"(tra));
      asm volatile("ds_read_b64_tr_b16 %0, %1 offset:1056" : "=v"(ta2) : "v"(tra));
      asm volatile("ds_read_b64_tr_b16 %0, %1 offset:4224" : "=v"(tb2) : "v"(tra));
      asm volatile("s_waitcnt lgkmcnt(0)" ::: "memory");
      __builtin_amdgcn_sched_barrier(0);
      union { u16 s[8]; f16x8 v; } B0, B1, B2;
#pragma unroll
      for (int j = 0; j < 4; ++j) {
        B0.s[j] = ta0[j]; B0.s[4 + j] = tb0[j];
        B1.s[j] = ta1[j]; B1.s[4 + j] = tb1[j];
        B2.s[j] = ta2[j]; B2.s[4 + j] = tb2[j];
      }
      ctx[0] = mfma16f(PA.v, B0.v, ctx[0]);
      ctx[1] = mfma16f(PA.v, B1.v, ctx[1]);
      ctx[2] = mfma16f(PA.v, B2.v, ctx[2]);
    }
    {
      u16x4 ta3, tb3, ta4, tb4;
      asm volatile("ds_read_b64_tr_b16 %0, %1 offset:1584" : "=v"(ta3) : "v"(tra));
      asm volatile("ds_read_b64_tr_b16 %0, %1 offset:4752" : "=v"(tb3) : "v"(tra));
      asm volatile("ds_read_b64_tr_b16 %0, %1 offset:2112" : "=v"(ta4) : "v"(tra));
      asm volatile("ds_read_b64_tr_b16 %0, %1 offset:5280" : "=v"(tb4) : "v"(tra));
      asm volatile("s_waitcnt lgkmcnt(0)" ::: "memory");
      __builtin_amdgcn_sched_barrier(0);
      union { u16 s[8]; f16x8 v; } B3, B4;
#pragma unroll
      for (int j = 0; j < 4; ++j) {
        B3.s[j] = ta3[j]; B3.s[4 + j] = tb3[j];
        B4.s[j] = ta4[j]; B4.s[4 + j] = tb4[j];
      }
      ctx[3] = mfma16f(PA.v, B3.v, ctx[3]);
      ctx[4] = mfma16f(PA.v, B4.v, ctx[4]);
    }

    if (hn) { STAGE_WRITE(nxt); }
    __syncthreads();
  }

  // ---------- epilogue: reduce lr, merge 4 s-slices, normalize, write ----------
  lr += __shfl_xor(lr, 16);
  lr += __shfl_xor(lr, 32);
  if (g == 0) {
    mst[sq * 64 + 16 * pp + l15] = mr;
    lst[sq * 64 + 16 * pp + l15] = lr;
  }
  __syncthreads();
  float F;
  {
    const int pi = 16 * pp + l15;
    float M = fmaxf(fmaxf(mst[pi], mst[64 + pi]), fmaxf(mst[128 + pi], mst[192 + pi]));
    F = E2(mr - M);
  }
  float gg[4];
#pragma unroll
  for (int rr = 0; rr < 4; ++rr) gg[rr] = __shfl(F, 4 * g + rr);
  float* cacc = (float*)smem;  // [64][84]
  for (int qq = 0; qq < 4; ++qq) {
    if (sq == qq) {
#pragma unroll
      for (int n = 0; n < 5; ++n) {
#pragma unroll
        for (int rr = 0; rr < 4; ++rr) {
          const int row = 16 * pp + 4 * g + rr;
          const int col = 16 * n + l15;
          float v = ctx[n][rr] * gg[rr];
          if (qq == 0) cacc[row * 84 + col] = v;
          else         cacc[row * 84 + col] += v;
        }
      }
    }
    __syncthreads();
  }
  {
    const int op = tid >> 4, oc = tid & 15;
    float Mv = fmaxf(fmaxf(mst[op], mst[64 + op]), fmaxf(mst[128 + op], mst[192 + op]));
    float Lv = lst[op] * E2(mst[op] - Mv) + lst[64 + op] * E2(mst[64 + op] - Mv)
             + lst[128 + op] * E2(mst[128 + op] - Mv) + lst[192 + op] * E2(mst[192 + op] - Mv);
    float inv = 1.0f / Lv;
    float* orow = out + ((size_t)b * NP + op) * ND + oc * 5;
    const float* crow = cacc + op * 84 + oc * 5;
#pragma unroll
    for (int i = 0; i < 5; ++i) orow[i] = crow[i] * inv;
  }
}

extern "C" void kernel_launch(void* const* d_in, const int* in_sizes, int n_in,
                              void* d_out, int out_size, void* d_ws, size_t ws_size,
                              hipStream_t stream) {
  (void)in_sizes; (void)n_in; (void)out_size; (void)d_ws; (void)ws_size;
  const float* enc  = (const float*)d_in[0];
  const float* dec  = (const float*)d_in[1];
  const int*   mask = (const int*)d_in[2];
  const float* W    = (const float*)d_in[3];
  float* out = (float*)d_out;
  DecoderAttention_62989990363717_kernel<<<dim3(NB), dim3(NTHREADS), 0, stream>>>(
      enc, dec, mask, W, out);
}